// Round 8
// baseline (659.885 us; speedup 1.0000x reference)
//
#include <hip/hip_runtime.h>
#include <cstdint>

#define N_NODES 100000
#define N_EDGES 3200000
#define BSZ     64                // dst nodes per bucket (single-owner, merge-free)
#define NBUCK   1563              // ceil(N_NODES / 64)
#define NPAD    (NBUCK * BSZ)     // 100032
#define NQUAD   4
#define QSTEP   25000             // src quadrant width
#define QCAP    1536              // LDS queue capacity (quadrant avg ~512, max ~700)
#define ACCSTRIDE 2816            // 64*32 max + 64*12 sum
#define K13_BLOCKS 256
#define K13_CHUNK  12500          // 256 * 12500 = 3.2M exactly

// ---- float <-> order-preserving unsigned (signed-float max via uint max) ----
__device__ __forceinline__ unsigned flipf(float f) {
    unsigned u = __float_as_uint(f);
    return (u & 0x80000000u) ? ~u : (u | 0x80000000u);
}
__device__ __forceinline__ float unflipf(unsigned v) {
    unsigned u = (v & 0x80000000u) ? (v & 0x7FFFFFFFu) : ~v;
    return __uint_as_float(u);
}
__device__ __forceinline__ int2 nt_load_rec(const int2* p) {
    unsigned long long v = __builtin_nontemporal_load((const unsigned long long*)p);
    return make_int2((int)(unsigned)(v & 0xFFFFFFFFull), (int)(unsigned)(v >> 32));
}

// ---------------- K1: per-bucket edge counts (dst only) ----------------
__global__ __launch_bounds__(256) void k1_count(const int* __restrict__ dst,
                                                int* __restrict__ total) {
    __shared__ int hist[NBUCK];
    for (int t = threadIdx.x; t < NBUCK; t += 256) hist[t] = 0;
    __syncthreads();
    int e0 = blockIdx.x * K13_CHUNK;
    for (int k = threadIdx.x; k < K13_CHUNK; k += 256)
        atomicAdd(&hist[__builtin_nontemporal_load(&dst[e0 + k]) >> 6], 1);
    __syncthreads();
    for (int t = threadIdx.x; t < NBUCK; t += 256) {
        int c = hist[t];
        if (c) atomicAdd(&total[t], c);
    }
}

// ---------------- K2: exclusive scan over NBUCK ----------------
__global__ __launch_bounds__(512) void k2_scan(const int* __restrict__ total,
                                               int* __restrict__ bucketBase,
                                               int* __restrict__ cursor) {
    __shared__ int part[512];
    int t = threadIdx.x;
    int base = t * 4;
    int v0 = (base     < NBUCK) ? total[base]     : 0;
    int v1 = (base + 1 < NBUCK) ? total[base + 1] : 0;
    int v2 = (base + 2 < NBUCK) ? total[base + 2] : 0;
    int v3 = (base + 3 < NBUCK) ? total[base + 3] : 0;
    int s = v0 + v1 + v2 + v3;
    part[t] = s;
    __syncthreads();
    for (int off = 1; off < 512; off <<= 1) {
        int u = (t >= off) ? part[t - off] : 0;
        __syncthreads();
        part[t] += u;
        __syncthreads();
    }
    int ex = part[t] - s;
    if (base     < NBUCK) { bucketBase[base]     = ex;                cursor[base]     = ex; }
    if (base + 1 < NBUCK) { bucketBase[base + 1] = ex + v0;           cursor[base + 1] = ex + v0; }
    if (base + 2 < NBUCK) { bucketBase[base + 2] = ex + v0 + v1;      cursor[base + 2] = ex + v0 + v1; }
    if (base + 3 < NBUCK) { bucketBase[base + 3] = ex + v0 + v1 + v2; cursor[base + 3] = ex + v0 + v1 + v2; }
    if (t == 511) bucketBase[NBUCK] = part[511];
}

// ---------------- K3: scatter edges into bucket-contiguous packed records ----------------
// record: int2 { (src<<6) | (dst&63), bits(norm) }
__global__ __launch_bounds__(256) void k3_scatter(const int* __restrict__ ei,
                                                  const float* __restrict__ norm,
                                                  int* __restrict__ cursor,
                                                  int2* __restrict__ ebuf) {
    __shared__ int hist[NBUCK];
    __shared__ int lcur[NBUCK];
    for (int t = threadIdx.x; t < NBUCK; t += 256) hist[t] = 0;
    __syncthreads();
    int e0 = blockIdx.x * K13_CHUNK;
    for (int k = threadIdx.x; k < K13_CHUNK; k += 256)
        atomicAdd(&hist[__builtin_nontemporal_load(&ei[N_EDGES + e0 + k]) >> 6], 1);
    __syncthreads();
    for (int t = threadIdx.x; t < NBUCK; t += 256) {
        int c = hist[t];
        lcur[t] = c ? atomicAdd(&cursor[t], c) : 0;
    }
    __syncthreads();
    for (int k = threadIdx.x; k < K13_CHUNK; k += 256) {
        int e = e0 + k;
        int s = __builtin_nontemporal_load(&ei[e]);
        int d = __builtin_nontemporal_load(&ei[N_EDGES + e]);
        float w = __builtin_nontemporal_load(&norm[e]);
        int r = atomicAdd(&lcur[d >> 6], 1);
        ebuf[r] = make_int2((s << 6) | (d & 63), __float_as_int(w));
    }
}

// -------- K4: layer-1 aggregation (LDS, merge-free) -> combined 128B row table --------
// row i (32 floats): [0..12) z2, [12]=x0,[13]=x1,[14]=a0,[15]=a1,[16]=m0,[17]=m1, pad
// sw: w1m_l[0..48) b1m[48..72) w1m_r[72..120) w1x_l[120..136) b1x[136..144)
//     w1x_r[144..160) w2m_l[160..544)
__global__ __launch_bounds__(256) void k4_fused(
        const float2* __restrict__ x, const int2* __restrict__ ebuf,
        const int* __restrict__ bucketBase,
        const float* __restrict__ w1m_l, const float* __restrict__ b1m,
        const float* __restrict__ w1m_r,
        const float* __restrict__ w1x_l, const float* __restrict__ b1x,
        const float* __restrict__ w1x_r,
        const float* __restrict__ w2m_l,
        float* __restrict__ table) {
    __shared__ float sw[544];
    __shared__ float    s_sum0[BSZ], s_sum1[BSZ];   // per-feature arrays: bank-conflict-free
    __shared__ unsigned s_max0[BSZ], s_max1[BSZ];
    for (int t = threadIdx.x; t < 544; t += 256) {
        float v;
        if (t < 48)       v = w1m_l[t];
        else if (t < 72)  v = b1m[t - 48];
        else if (t < 120) v = w1m_r[t - 72];
        else if (t < 136) v = w1x_l[t - 120];
        else if (t < 144) v = b1x[t - 136];
        else if (t < 160) v = w1x_r[t - 144];
        else              v = w2m_l[t - 160];
        sw[t] = v;
    }
    if (threadIdx.x < BSZ) {
        s_sum0[threadIdx.x] = 0.0f; s_sum1[threadIdx.x] = 0.0f;
        s_max0[threadIdx.x] = 0u;   s_max1[threadIdx.x] = 0u;
    }
    __syncthreads();

    int b = blockIdx.x;
    int beg = bucketBase[b], end = bucketBase[b + 1];

    int e = beg + threadIdx.x;
    for (; e + 768 < end; e += 1024) {
        int2 r0 = nt_load_rec(&ebuf[e]),       r1 = nt_load_rec(&ebuf[e + 256]);
        int2 r2 = nt_load_rec(&ebuf[e + 512]), r3 = nt_load_rec(&ebuf[e + 768]);
        float2 x0 = x[r0.x >> 6], x1 = x[r1.x >> 6], x2 = x[r2.x >> 6], x3 = x[r3.x >> 6];
        float w0 = __int_as_float(r0.y), w1 = __int_as_float(r1.y);
        float w2 = __int_as_float(r2.y), w3 = __int_as_float(r3.y);
        int l0 = r0.x & 63, l1 = r1.x & 63, l2 = r2.x & 63, l3 = r3.x & 63;
        atomicAdd(&s_sum0[l0], x0.x * w0); atomicAdd(&s_sum1[l0], x0.y * w0);
        atomicAdd(&s_sum0[l1], x1.x * w1); atomicAdd(&s_sum1[l1], x1.y * w1);
        atomicAdd(&s_sum0[l2], x2.x * w2); atomicAdd(&s_sum1[l2], x2.y * w2);
        atomicAdd(&s_sum0[l3], x3.x * w3); atomicAdd(&s_sum1[l3], x3.y * w3);
        atomicMax(&s_max0[l0], flipf(x0.x)); atomicMax(&s_max1[l0], flipf(x0.y));
        atomicMax(&s_max0[l1], flipf(x1.x)); atomicMax(&s_max1[l1], flipf(x1.y));
        atomicMax(&s_max0[l2], flipf(x2.x)); atomicMax(&s_max1[l2], flipf(x2.y));
        atomicMax(&s_max0[l3], flipf(x3.x)); atomicMax(&s_max1[l3], flipf(x3.y));
    }
    for (; e < end; e += 256) {
        int2 r = nt_load_rec(&ebuf[e]);
        float2 xs = x[r.x >> 6];
        float w = __int_as_float(r.y);
        int l = r.x & 63;
        atomicAdd(&s_sum0[l], xs.x * w); atomicAdd(&s_sum1[l], xs.y * w);
        atomicMax(&s_max0[l], flipf(xs.x)); atomicMax(&s_max1[l], flipf(xs.y));
    }
    __syncthreads();

    int t = threadIdx.x;
    if (t >= BSZ) return;
    int i = b * BSZ + t;
    if (i >= N_NODES) return;

    float2 xi = x[i];
    float a0 = s_sum0[t], a1 = s_sum1[t];
    unsigned m0u = s_max0[t], m1u = s_max1[t];
    float m0 = m0u ? unflipf(m0u) : 0.0f;   // 0 sentinel == empty segment -> 0
    float m1 = m1u ? unflipf(m1u) : 0.0f;

    float hh[32];
#pragma unroll
    for (int k = 0; k < 24; k++) {
        float v = sw[48 + k] + sw[2 * k] * a0 + sw[2 * k + 1] * a1
                + sw[72 + 2 * k] * xi.x + sw[72 + 2 * k + 1] * xi.y;
        hh[k] = fmaxf(v, 0.0f);
    }
#pragma unroll
    for (int k = 0; k < 8; k++) {
        float v = sw[136 + k] + sw[120 + 2 * k] * m0 + sw[120 + 2 * k + 1] * m1
                + sw[144 + 2 * k] * xi.x + sw[144 + 2 * k + 1] * xi.y;
        hh[24 + k] = fmaxf(v, 0.0f);
    }

    float zz[12];
#pragma unroll
    for (int j = 0; j < 12; j++) {
        float v = 0.0f;
#pragma unroll
        for (int k = 0; k < 32; k++) v += hh[k] * sw[160 + j * 32 + k];
        zz[j] = v;
    }

    float4* row = (float4*)(table + ((size_t)i << 5));
    row[0] = make_float4(zz[0], zz[1], zz[2],  zz[3]);
    row[1] = make_float4(zz[4], zz[5], zz[6],  zz[7]);
    row[2] = make_float4(zz[8], zz[9], zz[10], zz[11]);
    row[3] = make_float4(xi.x, xi.y, a0, a1);
    row[4] = make_float4(m0, m1, 0.0f, 0.0f);
    row[5] = make_float4(0.0f, 0.0f, 0.0f, 0.0f);   // full-line write: no RMW
    row[6] = make_float4(0.0f, 0.0f, 0.0f, 0.0f);
    row[7] = make_float4(0.0f, 0.0f, 0.0f, 0.0f);
}

// ---- per-edge layer-2 work: gather one row line, sum + recomputed-h1 max ----
__device__ __forceinline__ void k5_edge(int2 r, const float* __restrict__ table,
        unsigned* s2x, float* s2s, int f32, int goff,
        float c0, float c1, float c2, float c3, float c4) {
    int src = r.x >> 6, local = r.x & 63;
    const float* row = table + ((size_t)src << 5);
    float2 xv = *(const float2*)(row + 12);
    float2 gv = *(const float2*)(row + goff);
    float v = fmaxf(c0 + c1 * gv.x + c2 * gv.y + c3 * xv.x + c4 * xv.y, 0.0f);
    atomicMax(&s2x[local * 32 + f32], __float_as_uint(v));
    if (f32 < 12) {
        float z = row[f32];
        atomicAdd(&s2s[local * 12 + f32], z * __int_as_float(r.y));
    }
}

// -------- K5: layer-2 quadrant pass. 4 sequential launches, all XCDs share one
//          3.2MB table slice per launch. Owner-block acc merge (no atomics).
//          FINAL launch fuses node2 + MLP epilogue. --------
template<bool LOAD_ACC, bool FINAL>
__global__ __launch_bounds__(256) void k5_quad(
        const float* __restrict__ table, const int2* __restrict__ ebuf,
        const int* __restrict__ bucketBase, float* __restrict__ acc,
        int qlo, int qhi,
        const float* __restrict__ w1m_l, const float* __restrict__ b1m,
        const float* __restrict__ w1m_r,
        const float* __restrict__ w1x_l, const float* __restrict__ b1x,
        const float* __restrict__ w1x_r,
        const float* __restrict__ b2m, const float* __restrict__ w2m_r,
        const float* __restrict__ w2x_l, const float* __restrict__ b2x,
        const float* __restrict__ w2x_r,
        const float* __restrict__ w3, const float* __restrict__ b3,
        const float* __restrict__ w4, const float* __restrict__ b4,
        const float* __restrict__ w5, const float* __restrict__ b5,
        float* __restrict__ out) {
    __shared__ float sw[FINAL ? 1003 : 160];
    __shared__ unsigned s2x[BSZ * 32];   // 8 KB
    __shared__ float    s2s[BSZ * 12];   // 3 KB
    __shared__ int2     queue[QCAP];     // 12 KB
    __shared__ int      qcount;

    const int NSW = FINAL ? 1003 : 160;
    for (int t = threadIdx.x; t < NSW; t += 256) {
        float v;
        if (t < 48)        v = w1m_l[t];
        else if (t < 72)   v = b1m[t - 48];
        else if (t < 120)  v = w1m_r[t - 72];
        else if (t < 136)  v = w1x_l[t - 120];
        else if (t < 144)  v = b1x[t - 136];
        else if (t < 160)  v = w1x_r[t - 144];
        else if (t < 172)  v = b2m[t - 160];
        else if (t < 556)  v = w2m_r[t - 172];
        else if (t < 684)  v = w2x_l[t - 556];
        else if (t < 688)  v = b2x[t - 684];
        else if (t < 816)  v = w2x_r[t - 688];
        else if (t < 944)  v = w3[t - 816];
        else if (t < 952)  v = b3[t - 944];
        else if (t < 992)  v = w4[t - 952];
        else if (t < 997)  v = b4[t - 992];
        else if (t < 1002) v = w5[t - 997];
        else               v = b5[0];
        sw[t] = v;
    }
    for (int t = threadIdx.x; t < BSZ * 32; t += 256) s2x[t] = 0u;
    for (int t = threadIdx.x; t < BSZ * 12; t += 256) s2s[t] = 0.0f;
    if (threadIdx.x == 0) qcount = 0;
    __syncthreads();

    // per-lane layer-1 feature constants (f32 = lane & 31)
    int f32 = threadIdx.x & 31;
    float c0, c1, c2, c3, c4;
    int goff;
    if (f32 < 24) {
        c0 = sw[48 + f32];    c1 = sw[2 * f32];       c2 = sw[2 * f32 + 1];
        c3 = sw[72 + 2 * f32]; c4 = sw[72 + 2 * f32 + 1];
        goff = 14;                           // (a0,a1)
    } else {
        int g = f32 - 24;
        c0 = sw[136 + g];     c1 = sw[120 + 2 * g];   c2 = sw[120 + 2 * g + 1];
        c3 = sw[144 + 2 * g]; c4 = sw[144 + 2 * g + 1];
        goff = 16;                           // (m0,m1)
    }

    int b = blockIdx.x;
    int beg = bucketBase[b], end = bucketBase[b + 1];

    // phase A: coalesced scan + quadrant filter into LDS queue
    for (int e = beg + threadIdx.x; e < end; e += 256) {
        int2 r = nt_load_rec(&ebuf[e]);
        int src = r.x >> 6;
        if (src >= qlo && src < qhi) {
            int idx = atomicAdd(&qcount, 1);
            if (idx < QCAP) queue[idx] = r;
            else k5_edge(r, table, s2x, s2s, f32, goff, c0, c1, c2, c3, c4);
        }
    }
    __syncthreads();
    int n = min(qcount, QCAP);

    // phase B: 32 lanes/edge over queue, 4-unrolled
    int eg = threadIdx.x >> 5;               // 8 edge-groups
    int e = eg;
    for (; e + 24 < n; e += 32) {
        int2 r0 = queue[e], r1 = queue[e + 8], r2 = queue[e + 16], r3 = queue[e + 24];
        k5_edge(r0, table, s2x, s2s, f32, goff, c0, c1, c2, c3, c4);
        k5_edge(r1, table, s2x, s2s, f32, goff, c0, c1, c2, c3, c4);
        k5_edge(r2, table, s2x, s2s, f32, goff, c0, c1, c2, c3, c4);
        k5_edge(r3, table, s2x, s2s, f32, goff, c0, c1, c2, c3, c4);
    }
    for (; e < n; e += 8)
        k5_edge(queue[e], table, s2x, s2s, f32, goff, c0, c1, c2, c3, c4);
    __syncthreads();

    unsigned* accu = (unsigned*)(acc + (size_t)b * ACCSTRIDE);
    float*    accf = acc + (size_t)b * ACCSTRIDE + 2048;

    if (!FINAL) {
        // owner-block merge: plain coalesced load-merge-store, no atomics
        for (int u = threadIdx.x; u < 2048; u += 256) {
            unsigned m = s2x[u];
            if (LOAD_ACC) m = max(m, accu[u]);
            accu[u] = m;
        }
        for (int u = threadIdx.x; u < 768; u += 256) {
            float v = s2s[u];
            if (LOAD_ACC) v += accf[u];
            accf[u] = v;
        }
        return;
    }

    // FINAL: merge acc into LDS, then fused node2 + MLP epilogue
    for (int u = threadIdx.x; u < 2048; u += 256) s2x[u] = max(s2x[u], accu[u]);
    for (int u = threadIdx.x; u < 768; u += 256)  s2s[u] += accf[u];
    __syncthreads();

    int t = threadIdx.x;
    if (t >= BSZ) return;
    int i = b * BSZ + t;
    if (i >= N_NODES) return;

    const float* row = table + ((size_t)i << 5);
    float4 pf = *(const float4*)(row + 12);          // x0,x1,a0,a1
    float2 pm = *(const float2*)(row + 16);          // m0,m1
    float xi0 = pf.x, xi1 = pf.y, a0 = pf.z, a1 = pf.w, m0 = pm.x, m1 = pm.y;

    float hh[32];
#pragma unroll
    for (int k = 0; k < 24; k++) {
        float v = sw[48 + k] + sw[2 * k] * a0 + sw[2 * k + 1] * a1
                + sw[72 + 2 * k] * xi0 + sw[72 + 2 * k + 1] * xi1;
        hh[k] = fmaxf(v, 0.0f);
    }
#pragma unroll
    for (int k = 0; k < 8; k++) {
        float v = sw[136 + k] + sw[120 + 2 * k] * m0 + sw[120 + 2 * k + 1] * m1
                + sw[144 + 2 * k] * xi0 + sw[144 + 2 * k + 1] * xi1;
        hh[24 + k] = fmaxf(v, 0.0f);
    }

    float ax[32];
#pragma unroll
    for (int k = 0; k < 32; k++) ax[k] = __uint_as_float(s2x[t * 32 + k]);

    float h2[16];
#pragma unroll
    for (int j = 0; j < 12; j++) {
        float v = s2s[t * 12 + j] + sw[160 + j];
#pragma unroll
        for (int k = 0; k < 32; k++) v += hh[k] * sw[172 + j * 32 + k];
        h2[j] = fmaxf(v, 0.0f);
    }
#pragma unroll
    for (int j = 0; j < 4; j++) {
        float v = sw[684 + j];
#pragma unroll
        for (int k = 0; k < 32; k++)
            v += ax[k] * sw[556 + j * 32 + k] + hh[k] * sw[688 + j * 32 + k];
        h2[12 + j] = fmaxf(v, 0.0f);
    }

    float t3[8];
#pragma unroll
    for (int j = 0; j < 8; j++) {
        float v = sw[944 + j];
#pragma unroll
        for (int k = 0; k < 16; k++) v += h2[k] * sw[816 + j * 16 + k];
        t3[j] = fmaxf(v, 0.0f);
    }
    float t4[5];
#pragma unroll
    for (int j = 0; j < 5; j++) {
        float v = sw[992 + j];
#pragma unroll
        for (int k = 0; k < 8; k++) v += t3[k] * sw[952 + j * 8 + k];
        t4[j] = fmaxf(v, 0.0f);
    }
    float o = sw[1002];
#pragma unroll
    for (int k = 0; k < 5; k++) o += t4[k] * sw[997 + k];
    out[i] = o;
}

extern "C" void kernel_launch(void* const* d_in, const int* in_sizes, int n_in,
                              void* d_out, int out_size, void* d_ws, size_t ws_size,
                              hipStream_t stream) {
    const float* x     = (const float*)d_in[0];
    const int*   ei    = (const int*)d_in[1];
    const float* norm  = (const float*)d_in[2];
    const float* w1m_l = (const float*)d_in[3];
    const float* b1m   = (const float*)d_in[4];
    const float* w1m_r = (const float*)d_in[5];
    const float* w1x_l = (const float*)d_in[6];
    const float* b1x   = (const float*)d_in[7];
    const float* w1x_r = (const float*)d_in[8];
    const float* w2m_l = (const float*)d_in[9];
    const float* b2m   = (const float*)d_in[10];
    const float* w2m_r = (const float*)d_in[11];
    const float* w2x_l = (const float*)d_in[12];
    const float* b2x   = (const float*)d_in[13];
    const float* w2x_r = (const float*)d_in[14];
    const float* w3    = (const float*)d_in[15];
    const float* b3    = (const float*)d_in[16];
    const float* w4    = (const float*)d_in[17];
    const float* b4    = (const float*)d_in[18];
    const float* w5    = (const float*)d_in[19];
    const float* b5    = (const float*)d_in[20];
    float* out = (float*)d_out;

    // workspace (~56 MB)
    char* ws = (char*)d_ws;
    int2*  ebuf  = (int2*)ws;                                  // 25.6 MB
    float* table = (float*)(ws + (size_t)N_EDGES * 8);         // NPAD*32*4 = 12.8 MB
    float* acc   = table + (size_t)NPAD * 32;                  // NBUCK*2816*4 = 17.6 MB
    int*   total      = (int*)(acc + (size_t)NBUCK * ACCSTRIDE);
    int*   bucketBase = total + NBUCK;
    int*   cursor     = bucketBase + NBUCK + 1;

    hipMemsetAsync(total, 0, NBUCK * sizeof(int), stream);

    k1_count  <<<K13_BLOCKS, 256, 0, stream>>>(ei + N_EDGES, total);
    k2_scan   <<<1, 512, 0, stream>>>(total, bucketBase, cursor);
    k3_scatter<<<K13_BLOCKS, 256, 0, stream>>>(ei, norm, cursor, ebuf);
    k4_fused  <<<NBUCK, 256, 0, stream>>>((const float2*)x, ebuf, bucketBase,
                                          w1m_l, b1m, w1m_r, w1x_l, b1x, w1x_r,
                                          w2m_l, table);
    k5_quad<false, false><<<NBUCK, 256, 0, stream>>>(table, ebuf, bucketBase, acc,
        0 * QSTEP, 1 * QSTEP, w1m_l, b1m, w1m_r, w1x_l, b1x, w1x_r,
        b2m, w2m_r, w2x_l, b2x, w2x_r, w3, b3, w4, b4, w5, b5, out);
    k5_quad<true, false><<<NBUCK, 256, 0, stream>>>(table, ebuf, bucketBase, acc,
        1 * QSTEP, 2 * QSTEP, w1m_l, b1m, w1m_r, w1x_l, b1x, w1x_r,
        b2m, w2m_r, w2x_l, b2x, w2x_r, w3, b3, w4, b4, w5, b5, out);
    k5_quad<true, false><<<NBUCK, 256, 0, stream>>>(table, ebuf, bucketBase, acc,
        2 * QSTEP, 3 * QSTEP, w1m_l, b1m, w1m_r, w1x_l, b1x, w1x_r,
        b2m, w2m_r, w2x_l, b2x, w2x_r, w3, b3, w4, b4, w5, b5, out);
    k5_quad<true, true><<<NBUCK, 256, 0, stream>>>(table, ebuf, bucketBase, acc,
        3 * QSTEP, 4 * QSTEP, w1m_l, b1m, w1m_r, w1x_l, b1x, w1x_r,
        b2m, w2m_r, w2x_l, b2x, w2x_r, w3, b3, w4, b4, w5, b5, out);
}

// Round 9
// 628.607 us; speedup vs baseline: 1.0498x; 1.0498x over previous
//
#include <hip/hip_runtime.h>
#include <cstdint>

#define N_NODES 100000
#define N_EDGES 3200000
#define BSZ     64                // dst nodes per bucket
#define NBUCK   1563              // ceil(N_NODES / 64)
#define NPAD    (NBUCK * BSZ)     // 100032
#define SORTCAP 4096              // k3b LDS capacity (bucket avg 2048, >45 sigma margin)
#define K13_BLOCKS 128
#define K13_CHUNK  25000          // 128 * 25000 = 3.2M exactly

// ---- float <-> order-preserving unsigned (signed-float max via uint max) ----
__device__ __forceinline__ unsigned flipf(float f) {
    unsigned u = __float_as_uint(f);
    return (u & 0x80000000u) ? ~u : (u | 0x80000000u);   // never returns 0
}
__device__ __forceinline__ float unflipf(unsigned v) {
    unsigned u = (v & 0x80000000u) ? (v & 0x7FFFFFFFu) : ~v;
    return __uint_as_float(u);
}
__device__ __forceinline__ int2 nt_load_rec(const int2* p) {
    unsigned long long v = __builtin_nontemporal_load((const unsigned long long*)p);
    return make_int2((int)(unsigned)(v & 0xFFFFFFFFull), (int)(unsigned)(v >> 32));
}

// ---------------- K1: per-bucket edge counts (dst only) ----------------
__global__ __launch_bounds__(256) void k1_count(const int* __restrict__ dst,
                                                int* __restrict__ total) {
    __shared__ int hist[NBUCK];
    for (int t = threadIdx.x; t < NBUCK; t += 256) hist[t] = 0;
    __syncthreads();
    int e0 = blockIdx.x * K13_CHUNK;
    for (int k = threadIdx.x; k < K13_CHUNK; k += 256)
        atomicAdd(&hist[__builtin_nontemporal_load(&dst[e0 + k]) >> 6], 1);
    __syncthreads();
    for (int t = threadIdx.x; t < NBUCK; t += 256) {
        int c = hist[t];
        if (c) atomicAdd(&total[t], c);
    }
}

// ---------------- K2: exclusive scan over NBUCK ----------------
__global__ __launch_bounds__(512) void k2_scan(const int* __restrict__ total,
                                               int* __restrict__ bucketBase,
                                               int* __restrict__ cursor) {
    __shared__ int part[512];
    int t = threadIdx.x;
    int base = t * 4;
    int v0 = (base     < NBUCK) ? total[base]     : 0;
    int v1 = (base + 1 < NBUCK) ? total[base + 1] : 0;
    int v2 = (base + 2 < NBUCK) ? total[base + 2] : 0;
    int v3 = (base + 3 < NBUCK) ? total[base + 3] : 0;
    int s = v0 + v1 + v2 + v3;
    part[t] = s;
    __syncthreads();
    for (int off = 1; off < 512; off <<= 1) {
        int u = (t >= off) ? part[t - off] : 0;
        __syncthreads();
        part[t] += u;
        __syncthreads();
    }
    int ex = part[t] - s;
    if (base     < NBUCK) { bucketBase[base]     = ex;                cursor[base]     = ex; }
    if (base + 1 < NBUCK) { bucketBase[base + 1] = ex + v0;           cursor[base + 1] = ex + v0; }
    if (base + 2 < NBUCK) { bucketBase[base + 2] = ex + v0 + v1;      cursor[base + 2] = ex + v0 + v1; }
    if (base + 3 < NBUCK) { bucketBase[base + 3] = ex + v0 + v1 + v2; cursor[base + 3] = ex + v0 + v1 + v2; }
    if (t == 511) bucketBase[NBUCK] = part[511];
}

// ---------------- K3: scatter edges into bucket-contiguous packed records ----------------
// record: int2 { (src<<6) | (dst&63), bits(norm) }
__global__ __launch_bounds__(256) void k3_scatter(const int* __restrict__ ei,
                                                  const float* __restrict__ norm,
                                                  int* __restrict__ cursor,
                                                  int2* __restrict__ ebuf) {
    __shared__ int hist[NBUCK];
    __shared__ int lcur[NBUCK];
    for (int t = threadIdx.x; t < NBUCK; t += 256) hist[t] = 0;
    __syncthreads();
    int e0 = blockIdx.x * K13_CHUNK;
    for (int k = threadIdx.x; k < K13_CHUNK; k += 256)
        atomicAdd(&hist[__builtin_nontemporal_load(&ei[N_EDGES + e0 + k]) >> 6], 1);
    __syncthreads();
    for (int t = threadIdx.x; t < NBUCK; t += 256) {
        int c = hist[t];
        lcur[t] = c ? atomicAdd(&cursor[t], c) : 0;
    }
    __syncthreads();
    for (int k = threadIdx.x; k < K13_CHUNK; k += 256) {
        int e = e0 + k;
        int s = __builtin_nontemporal_load(&ei[e]);
        int d = __builtin_nontemporal_load(&ei[N_EDGES + e]);
        float w = __builtin_nontemporal_load(&norm[e]);
        int r = atomicAdd(&lcur[d >> 6], 1);
        ebuf[r] = make_int2((s << 6) | (d & 63), __float_as_int(w));
    }
}

// ---------------- K3b: per-bucket LDS counting sort by dst node -> nodeBase ----------------
__global__ __launch_bounds__(256) void k3b_sort(const int* __restrict__ bucketBase,
                                                int2* __restrict__ ebuf,
                                                int* __restrict__ nodeBase) {
    __shared__ int2 recs[SORTCAP];           // 32 KB
    __shared__ int2 srt [SORTCAP];           // 32 KB
    __shared__ int cnt[BSZ], off[BSZ], cur[BSZ];
    int b = blockIdx.x;
    int beg = bucketBase[b], end = bucketBase[b + 1];
    int n = end - beg;
    if (threadIdx.x < BSZ) cnt[threadIdx.x] = 0;
    __syncthreads();
    for (int k = threadIdx.x; k < n; k += 256) {
        int2 r = ebuf[beg + k];
        recs[k] = r;
        atomicAdd(&cnt[r.x & 63], 1);
    }
    __syncthreads();
    if (threadIdx.x == 0) {
        int a = 0;
        for (int j = 0; j < BSZ; j++) { off[j] = a; cur[j] = a; a += cnt[j]; }
    }
    __syncthreads();
    for (int k = threadIdx.x; k < n; k += 256) {
        int2 r = recs[k];
        int p = atomicAdd(&cur[r.x & 63], 1);
        srt[p] = r;
    }
    __syncthreads();
    for (int k = threadIdx.x; k < n; k += 256) ebuf[beg + k] = srt[k];
    if (threadIdx.x < BSZ) nodeBase[b * BSZ + threadIdx.x] = beg + off[threadIdx.x];
    if (threadIdx.x == BSZ) nodeBase[b * BSZ + BSZ] = end;   // same value as next block's beg
}

// -------- K4: layer-1 wave-per-node register aggregation + node1 epilogue --------
// sw: w1m_l[0..48) b1m[48..72) w1m_r[72..120) w1x_l[120..136) b1x[136..144)
//     w1x_r[144..160) w2m_l[160..544)
__global__ __launch_bounds__(256) void k4_fused(
        const float* __restrict__ xf, const int2* __restrict__ ebuf,
        const int* __restrict__ nodeBase,
        const float* __restrict__ w1m_l, const float* __restrict__ b1m,
        const float* __restrict__ w1m_r,
        const float* __restrict__ w1x_l, const float* __restrict__ b1x,
        const float* __restrict__ w1x_r,
        const float* __restrict__ w2m_l,
        float* __restrict__ packed, float* __restrict__ z2) {
    __shared__ float sw[544];
    __shared__ float    s_a0[BSZ], s_a1[BSZ];
    __shared__ unsigned s_m0[BSZ], s_m1[BSZ];
    for (int t = threadIdx.x; t < 544; t += 256) {
        float v;
        if (t < 48)       v = w1m_l[t];
        else if (t < 72)  v = b1m[t - 48];
        else if (t < 120) v = w1m_r[t - 72];
        else if (t < 136) v = w1x_l[t - 120];
        else if (t < 144) v = b1x[t - 136];
        else if (t < 160) v = w1x_r[t - 144];
        else              v = w2m_l[t - 160];
        sw[t] = v;
    }
    __syncthreads();

    int b = blockIdx.x;
    int wv = threadIdx.x >> 6, lane = threadIdx.x & 63;
    int slot = lane >> 1, p = lane & 1;

    for (int t = wv; t < BSZ; t += 4) {
        int i = b * BSZ + t;
        int e0 = nodeBase[i], e1 = nodeBase[i + 1];
        float sum = 0.0f;
        unsigned mx = 0u;
        for (int e = e0 + slot; e < e1; e += 32) {
            int2 r = nt_load_rec(&ebuf[e]);
            float w = __int_as_float(r.y);
            float xv = xf[(size_t)(r.x >> 6) * 2 + p];
            sum += xv * w;
            mx = max(mx, flipf(xv));
        }
#pragma unroll
        for (int s = 2; s <= 32; s <<= 1) {
            sum += __shfl_xor(sum, s);
            unsigned o = (unsigned)__shfl_xor((int)mx, s);
            mx = max(mx, o);
        }
        if (lane == 0) { s_a0[t] = sum; s_m0[t] = mx; }
        if (lane == 1) { s_a1[t] = sum; s_m1[t] = mx; }
    }
    __syncthreads();

    int tt = threadIdx.x;
    if (tt >= BSZ) return;
    int i = b * BSZ + tt;
    if (i >= N_NODES) return;

    float xi0 = xf[2 * i], xi1 = xf[2 * i + 1];
    float a0 = s_a0[tt], a1 = s_a1[tt];
    unsigned m0u = s_m0[tt], m1u = s_m1[tt];
    float m0 = m0u ? unflipf(m0u) : 0.0f;    // 0 sentinel == empty segment -> 0
    float m1 = m1u ? unflipf(m1u) : 0.0f;

    float hh[32];
#pragma unroll
    for (int k = 0; k < 24; k++) {
        float v = sw[48 + k] + sw[2 * k] * a0 + sw[2 * k + 1] * a1
                + sw[72 + 2 * k] * xi0 + sw[72 + 2 * k + 1] * xi1;
        hh[k] = fmaxf(v, 0.0f);
    }
#pragma unroll
    for (int k = 0; k < 8; k++) {
        float v = sw[136 + k] + sw[120 + 2 * k] * m0 + sw[120 + 2 * k + 1] * m1
                + sw[144 + 2 * k] * xi0 + sw[144 + 2 * k + 1] * xi1;
        hh[24 + k] = fmaxf(v, 0.0f);
    }

    float4* pk = (float4*)(packed + ((size_t)i << 3));
    pk[0] = make_float4(xi0, xi1, a0, a1);
    pk[1] = make_float4(m0, m1, 0.0f, 0.0f);

    float zz[12];
#pragma unroll
    for (int j = 0; j < 12; j++) {
        float v = 0.0f;
#pragma unroll
        for (int k = 0; k < 32; k++) v += hh[k] * sw[160 + j * 32 + k];
        zz[j] = v;
    }
    float4* z2v = (float4*)(z2 + (size_t)i * 12);
    z2v[0] = make_float4(zz[0], zz[1], zz[2],  zz[3]);
    z2v[1] = make_float4(zz[4], zz[5], zz[6],  zz[7]);
    z2v[2] = make_float4(zz[8], zz[9], zz[10], zz[11]);
}

// ---- K5x helper: one edge's recomputed h1 feature value ----
__device__ __forceinline__ float k5x_val(const int2* __restrict__ ebuf, int e,
        const float* __restrict__ packed, int gsel,
        float c0, float c1, float c2, float c3, float c4) {
    int2 r = nt_load_rec(&ebuf[e]);
    const float* row = packed + ((size_t)(r.x >> 6) << 3);
    float2 xv = *(const float2*)(row);
    float2 gv = *(const float2*)(row + gsel);
    return c0 + c1 * gv.x + c2 * gv.y + c3 * xv.x + c4 * xv.y;
}

// -------- K5x: layer-2 MAX, wave-per-node, register accumulate, no atomics --------
__global__ __launch_bounds__(256) void k5x_max(
        const float* __restrict__ packed, const int2* __restrict__ ebuf,
        const int* __restrict__ nodeBase,
        const float* __restrict__ w1m_l, const float* __restrict__ b1m,
        const float* __restrict__ w1m_r,
        const float* __restrict__ w1x_l, const float* __restrict__ b1x,
        const float* __restrict__ w1x_r,
        float* __restrict__ agg2x) {
    int lane = threadIdx.x & 63;
    int f = lane & 31, h = lane >> 5;
    float c0, c1, c2, c3, c4;
    int gsel;
    if (f < 24) {
        c0 = b1m[f];
        c1 = w1m_l[2 * f]; c2 = w1m_l[2 * f + 1];
        c3 = w1m_r[2 * f]; c4 = w1m_r[2 * f + 1];
        gsel = 2;                            // (a0,a1)
    } else {
        int g = f - 24;
        c0 = b1x[g];
        c1 = w1x_l[2 * g]; c2 = w1x_l[2 * g + 1];
        c3 = w1x_r[2 * g]; c4 = w1x_r[2 * g + 1];
        gsel = 4;                            // (m0,m1)
    }

    int b = blockIdx.x;
    int wv = threadIdx.x >> 6;
    for (int t = wv; t < BSZ; t += 4) {
        int i = b * BSZ + t;
        if (i >= N_NODES) break;
        int e0 = nodeBase[i], e1 = nodeBase[i + 1];
        float mx = 0.0f;                     // relu floor == empty-segment 0
        int e = e0 + h;
        for (; e + 6 < e1; e += 8) {
            float v0 = k5x_val(ebuf, e,     packed, gsel, c0, c1, c2, c3, c4);
            float v1 = k5x_val(ebuf, e + 2, packed, gsel, c0, c1, c2, c3, c4);
            float v2 = k5x_val(ebuf, e + 4, packed, gsel, c0, c1, c2, c3, c4);
            float v3 = k5x_val(ebuf, e + 6, packed, gsel, c0, c1, c2, c3, c4);
            mx = fmaxf(mx, fmaxf(fmaxf(v0, v1), fmaxf(v2, v3)));
        }
        for (; e < e1; e += 2)
            mx = fmaxf(mx, k5x_val(ebuf, e, packed, gsel, c0, c1, c2, c3, c4));
        mx = fmaxf(mx, __shfl_xor(mx, 32));
        if (h == 0) agg2x[(size_t)i * 32 + f] = mx;
    }
}

// -------- K5s: layer-2 SUM wave-per-node + fused node2 + MLP epilogue --------
// sw: [0..160) layer1 tables; [160..1003) layer2+MLP (see index map below)
__global__ __launch_bounds__(256) void k5s_final(
        const float* __restrict__ z2g, const float* __restrict__ packed,
        const float* __restrict__ agg2x,
        const int2* __restrict__ ebuf, const int* __restrict__ nodeBase,
        const float* __restrict__ w1m_l, const float* __restrict__ b1m,
        const float* __restrict__ w1m_r,
        const float* __restrict__ w1x_l, const float* __restrict__ b1x,
        const float* __restrict__ w1x_r,
        const float* __restrict__ b2m, const float* __restrict__ w2m_r,
        const float* __restrict__ w2x_l, const float* __restrict__ b2x,
        const float* __restrict__ w2x_r,
        const float* __restrict__ w3, const float* __restrict__ b3,
        const float* __restrict__ w4, const float* __restrict__ b4,
        const float* __restrict__ w5, const float* __restrict__ b5,
        float* __restrict__ out) {
    __shared__ float sw[1003];
    __shared__ float s2s[BSZ * 12];
    for (int t = threadIdx.x; t < 1003; t += 256) {
        float v;
        if (t < 48)        v = w1m_l[t];
        else if (t < 72)   v = b1m[t - 48];
        else if (t < 120)  v = w1m_r[t - 72];
        else if (t < 136)  v = w1x_l[t - 120];
        else if (t < 144)  v = b1x[t - 136];
        else if (t < 160)  v = w1x_r[t - 144];
        else if (t < 172)  v = b2m[t - 160];
        else if (t < 556)  v = w2m_r[t - 172];
        else if (t < 684)  v = w2x_l[t - 556];
        else if (t < 688)  v = b2x[t - 684];
        else if (t < 816)  v = w2x_r[t - 688];
        else if (t < 944)  v = w3[t - 816];
        else if (t < 952)  v = b3[t - 944];
        else if (t < 992)  v = w4[t - 952];
        else if (t < 997)  v = b4[t - 992];
        else if (t < 1002) v = w5[t - 997];
        else               v = b5[0];
        sw[t] = v;
    }
    __syncthreads();

    int b = blockIdx.x;
    int wv = threadIdx.x >> 6, lane = threadIdx.x & 63;
    int g = lane >> 4, f = lane & 15;
    bool fa = (f < 12);

    for (int t = wv; t < BSZ; t += 4) {
        int i = b * BSZ + t;
        if (i >= N_NODES) break;
        int e0 = nodeBase[i], e1 = nodeBase[i + 1];
        float acc = 0.0f;
        int e = e0 + g;
        for (; e + 4 < e1; e += 8) {
            int2 ra = nt_load_rec(&ebuf[e]);
            int2 rb = nt_load_rec(&ebuf[e + 4]);
            if (fa) {
                acc += z2g[(size_t)(ra.x >> 6) * 12 + f] * __int_as_float(ra.y);
                acc += z2g[(size_t)(rb.x >> 6) * 12 + f] * __int_as_float(rb.y);
            }
        }
        for (; e < e1; e += 4) {
            int2 r = nt_load_rec(&ebuf[e]);
            if (fa) acc += z2g[(size_t)(r.x >> 6) * 12 + f] * __int_as_float(r.y);
        }
        acc += __shfl_xor(acc, 16);
        acc += __shfl_xor(acc, 32);
        if (lane < 12) s2s[t * 12 + lane] = acc;
    }
    __syncthreads();

    int tt = threadIdx.x;
    if (tt >= BSZ) return;
    int i = b * BSZ + tt;
    if (i >= N_NODES) return;

    const float4 pf = *(const float4*)(packed + ((size_t)i << 3));       // x0,x1,a0,a1
    const float2 pm = *(const float2*)(packed + ((size_t)i << 3) + 4);   // m0,m1
    float xi0 = pf.x, xi1 = pf.y, a0 = pf.z, a1 = pf.w, m0 = pm.x, m1 = pm.y;

    float hh[32];
#pragma unroll
    for (int k = 0; k < 24; k++) {
        float v = sw[48 + k] + sw[2 * k] * a0 + sw[2 * k + 1] * a1
                + sw[72 + 2 * k] * xi0 + sw[72 + 2 * k + 1] * xi1;
        hh[k] = fmaxf(v, 0.0f);
    }
#pragma unroll
    for (int k = 0; k < 8; k++) {
        float v = sw[136 + k] + sw[120 + 2 * k] * m0 + sw[120 + 2 * k + 1] * m1
                + sw[144 + 2 * k] * xi0 + sw[144 + 2 * k + 1] * xi1;
        hh[24 + k] = fmaxf(v, 0.0f);
    }

    float ax[32];
    const float4* axv = (const float4*)(agg2x + (size_t)i * 32);
#pragma unroll
    for (int q = 0; q < 8; q++) {
        float4 a = axv[q];
        ax[4 * q] = a.x; ax[4 * q + 1] = a.y; ax[4 * q + 2] = a.z; ax[4 * q + 3] = a.w;
    }

    float h2[16];
#pragma unroll
    for (int j = 0; j < 12; j++) {
        float v = s2s[tt * 12 + j] + sw[160 + j];
#pragma unroll
        for (int k = 0; k < 32; k++) v += hh[k] * sw[172 + j * 32 + k];
        h2[j] = fmaxf(v, 0.0f);
    }
#pragma unroll
    for (int j = 0; j < 4; j++) {
        float v = sw[684 + j];
#pragma unroll
        for (int k = 0; k < 32; k++)
            v += ax[k] * sw[556 + j * 32 + k] + hh[k] * sw[688 + j * 32 + k];
        h2[12 + j] = fmaxf(v, 0.0f);
    }

    float t3[8];
#pragma unroll
    for (int j = 0; j < 8; j++) {
        float v = sw[944 + j];
#pragma unroll
        for (int k = 0; k < 16; k++) v += h2[k] * sw[816 + j * 16 + k];
        t3[j] = fmaxf(v, 0.0f);
    }
    float t4[5];
#pragma unroll
    for (int j = 0; j < 5; j++) {
        float v = sw[992 + j];
#pragma unroll
        for (int k = 0; k < 8; k++) v += t3[k] * sw[952 + j * 8 + k];
        t4[j] = fmaxf(v, 0.0f);
    }
    float o = sw[1002];
#pragma unroll
    for (int k = 0; k < 5; k++) o += t4[k] * sw[997 + k];
    out[i] = o;
}

extern "C" void kernel_launch(void* const* d_in, const int* in_sizes, int n_in,
                              void* d_out, int out_size, void* d_ws, size_t ws_size,
                              hipStream_t stream) {
    const float* x     = (const float*)d_in[0];
    const int*   ei    = (const int*)d_in[1];
    const float* norm  = (const float*)d_in[2];
    const float* w1m_l = (const float*)d_in[3];
    const float* b1m   = (const float*)d_in[4];
    const float* w1m_r = (const float*)d_in[5];
    const float* w1x_l = (const float*)d_in[6];
    const float* b1x   = (const float*)d_in[7];
    const float* w1x_r = (const float*)d_in[8];
    const float* w2m_l = (const float*)d_in[9];
    const float* b2m   = (const float*)d_in[10];
    const float* w2m_r = (const float*)d_in[11];
    const float* w2x_l = (const float*)d_in[12];
    const float* b2x   = (const float*)d_in[13];
    const float* w2x_r = (const float*)d_in[14];
    const float* w3    = (const float*)d_in[15];
    const float* b3    = (const float*)d_in[16];
    const float* w4    = (const float*)d_in[17];
    const float* b4    = (const float*)d_in[18];
    const float* w5    = (const float*)d_in[19];
    const float* b5    = (const float*)d_in[20];
    float* out = (float*)d_out;

    // workspace (~46.9 MB)
    char* ws = (char*)d_ws;
    int2*  ebuf   = (int2*)ws;                               // 25.6 MB
    float* packed = (float*)(ws + (size_t)N_EDGES * 8);      // NPAD*8*4  = 3.2 MB
    float* z2     = packed + (size_t)NPAD * 8;               // NPAD*12*4 = 4.8 MB
    float* agg2x  = z2 + (size_t)NPAD * 12;                  // NPAD*32*4 = 12.8 MB
    int*   nodeBase   = (int*)(agg2x + (size_t)NPAD * 32);   // NPAD+1
    int*   total      = nodeBase + NPAD + 1;                 // NBUCK
    int*   bucketBase = total + NBUCK;                       // NBUCK+1
    int*   cursor     = bucketBase + NBUCK + 1;              // NBUCK

    hipMemsetAsync(total, 0, NBUCK * sizeof(int), stream);

    k1_count  <<<K13_BLOCKS, 256, 0, stream>>>(ei + N_EDGES, total);
    k2_scan   <<<1, 512, 0, stream>>>(total, bucketBase, cursor);
    k3_scatter<<<K13_BLOCKS, 256, 0, stream>>>(ei, norm, cursor, ebuf);
    k3b_sort  <<<NBUCK, 256, 0, stream>>>(bucketBase, ebuf, nodeBase);
    k4_fused  <<<NBUCK, 256, 0, stream>>>(x, ebuf, nodeBase,
                                          w1m_l, b1m, w1m_r, w1x_l, b1x, w1x_r,
                                          w2m_l, packed, z2);
    k5x_max   <<<NBUCK, 256, 0, stream>>>(packed, ebuf, nodeBase,
                                          w1m_l, b1m, w1m_r, w1x_l, b1x, w1x_r,
                                          agg2x);
    k5s_final <<<NBUCK, 256, 0, stream>>>(z2, packed, agg2x, ebuf, nodeBase,
                                          w1m_l, b1m, w1m_r, w1x_l, b1x, w1x_r,
                                          b2m, w2m_r, w2x_l, b2x, w2x_r,
                                          w3, b3, w4, b4, w5, b5, out);
}

// Round 10
// 515.819 us; speedup vs baseline: 1.2793x; 1.2187x over previous
//
#include <hip/hip_runtime.h>
#include <cstdint>

#define N_NODES 100000
#define N_EDGES 3200000
#define BSZ     64                // dst nodes per bucket
#define NBUCK   1563              // ceil(N_NODES / 64)
#define NPAD    (NBUCK * BSZ)     // 100032
#define NPAIR   (NPAD / 2)        // 50016 node-pairs for k5
#define SORTCAP 4096              // bucket avg 2048, std ~45 -> huge margin
#define K13_BLOCKS 128
#define K13_CHUNK  25000          // 128 * 25000 = 3.2M exactly
#define K5_BLOCKS  1024
#define K5_WAVES   (K5_BLOCKS * 4)

// ---- float <-> order-preserving unsigned (signed-float max via uint max) ----
__device__ __forceinline__ unsigned flipf(float f) {
    unsigned u = __float_as_uint(f);
    return (u & 0x80000000u) ? ~u : (u | 0x80000000u);   // never returns 0
}
__device__ __forceinline__ float unflipf(unsigned v) {
    unsigned u = (v & 0x80000000u) ? (v & 0x7FFFFFFFu) : ~v;
    return __uint_as_float(u);
}
__device__ __forceinline__ int2 nt_load_rec(const int2* p) {
    unsigned long long v = __builtin_nontemporal_load((const unsigned long long*)p);
    return make_int2((int)(unsigned)(v & 0xFFFFFFFFull), (int)(unsigned)(v >> 32));
}

// ---------------- K1: per-bucket edge counts (dst only) ----------------
__global__ __launch_bounds__(256) void k1_count(const int* __restrict__ dst,
                                                int* __restrict__ total) {
    __shared__ int hist[NBUCK];
    for (int t = threadIdx.x; t < NBUCK; t += 256) hist[t] = 0;
    __syncthreads();
    int e0 = blockIdx.x * K13_CHUNK;
    for (int k = threadIdx.x; k < K13_CHUNK; k += 256)
        atomicAdd(&hist[__builtin_nontemporal_load(&dst[e0 + k]) >> 6], 1);
    __syncthreads();
    for (int t = threadIdx.x; t < NBUCK; t += 256) {
        int c = hist[t];
        if (c) atomicAdd(&total[t], c);
    }
}

// ---------------- K2: exclusive scan over NBUCK ----------------
__global__ __launch_bounds__(512) void k2_scan(const int* __restrict__ total,
                                               int* __restrict__ bucketBase,
                                               int* __restrict__ cursor) {
    __shared__ int part[512];
    int t = threadIdx.x;
    int base = t * 4;
    int v0 = (base     < NBUCK) ? total[base]     : 0;
    int v1 = (base + 1 < NBUCK) ? total[base + 1] : 0;
    int v2 = (base + 2 < NBUCK) ? total[base + 2] : 0;
    int v3 = (base + 3 < NBUCK) ? total[base + 3] : 0;
    int s = v0 + v1 + v2 + v3;
    part[t] = s;
    __syncthreads();
    for (int off = 1; off < 512; off <<= 1) {
        int u = (t >= off) ? part[t - off] : 0;
        __syncthreads();
        part[t] += u;
        __syncthreads();
    }
    int ex = part[t] - s;
    if (base     < NBUCK) { bucketBase[base]     = ex;                cursor[base]     = ex; }
    if (base + 1 < NBUCK) { bucketBase[base + 1] = ex + v0;           cursor[base + 1] = ex + v0; }
    if (base + 2 < NBUCK) { bucketBase[base + 2] = ex + v0 + v1;      cursor[base + 2] = ex + v0 + v1; }
    if (base + 3 < NBUCK) { bucketBase[base + 3] = ex + v0 + v1 + v2; cursor[base + 3] = ex + v0 + v1 + v2; }
    if (t == 511) bucketBase[NBUCK] = part[511];
}

// ---------------- K3: scatter edges into bucket-contiguous packed records ----------------
// record: int2 { (src<<6) | (dst&63), bits(norm) }
__global__ __launch_bounds__(256) void k3_scatter(const int* __restrict__ ei,
                                                  const float* __restrict__ norm,
                                                  int* __restrict__ cursor,
                                                  int2* __restrict__ ebuf) {
    __shared__ int hist[NBUCK];
    __shared__ int lcur[NBUCK];
    for (int t = threadIdx.x; t < NBUCK; t += 256) hist[t] = 0;
    __syncthreads();
    int e0 = blockIdx.x * K13_CHUNK;
    for (int k = threadIdx.x; k < K13_CHUNK; k += 256)
        atomicAdd(&hist[__builtin_nontemporal_load(&ei[N_EDGES + e0 + k]) >> 6], 1);
    __syncthreads();
    for (int t = threadIdx.x; t < NBUCK; t += 256) {
        int c = hist[t];
        lcur[t] = c ? atomicAdd(&cursor[t], c) : 0;
    }
    __syncthreads();
    for (int k = threadIdx.x; k < K13_CHUNK; k += 256) {
        int e = e0 + k;
        int s = __builtin_nontemporal_load(&ei[e]);
        int d = __builtin_nontemporal_load(&ei[N_EDGES + e]);
        float w = __builtin_nontemporal_load(&norm[e]);
        int r = atomicAdd(&lcur[d >> 6], 1);
        ebuf[r] = make_int2((s << 6) | (d & 63), __float_as_int(w));
    }
}

// ---- K3b: per-bucket LDS counting sort by dst node + FUSED layer-1 aggregation ----
// writes node-sorted ebuf, nodeBase, and the packed per-node row:
// packed[i] (8 floats): x0,x1,a0,a1,m0,m1,pad,pad  (32 B, table = 3.2 MB L2-resident)
__global__ __launch_bounds__(256) void k3b_sort_agg(
        const float2* __restrict__ x, const int* __restrict__ bucketBase,
        int2* __restrict__ ebuf, int* __restrict__ nodeBase,
        float* __restrict__ packed) {
    __shared__ int2 recs[SORTCAP];           // 32 KB
    __shared__ int2 srt [SORTCAP];           // 32 KB
    __shared__ int cnt[BSZ], off_s[BSZ], cur[BSZ];
    __shared__ float    s_a0[BSZ], s_a1[BSZ];
    __shared__ unsigned s_m0[BSZ], s_m1[BSZ];
    int b = blockIdx.x;
    int beg = bucketBase[b], end = bucketBase[b + 1];
    int n = end - beg;
    if (threadIdx.x < BSZ) {
        cnt[threadIdx.x] = 0;
        s_a0[threadIdx.x] = 0.0f; s_a1[threadIdx.x] = 0.0f;
        s_m0[threadIdx.x] = 0u;   s_m1[threadIdx.x] = 0u;
    }
    __syncthreads();
    for (int k = threadIdx.x; k < n; k += 256) {
        int2 r = ebuf[beg + k];
        recs[k] = r;
        atomicAdd(&cnt[r.x & 63], 1);
    }
    __syncthreads();
    if (threadIdx.x == 0) {
        int a = 0;
        for (int j = 0; j < BSZ; j++) { off_s[j] = a; cur[j] = a; a += cnt[j]; }
    }
    __syncthreads();
    for (int k = threadIdx.x; k < n; k += 256) {
        int2 r = recs[k];
        int p = atomicAdd(&cur[r.x & 63], 1);
        srt[p] = r;
    }
    __syncthreads();
    // write back sorted + aggregate layer-1 (x gather: 0.8 MB, L2-resident)
    for (int k = threadIdx.x; k < n; k += 256) {
        int2 r = srt[k];
        ebuf[beg + k] = r;
        float2 xs = x[r.x >> 6];
        float w = __int_as_float(r.y);
        int l = r.x & 63;
        atomicAdd(&s_a0[l], xs.x * w);
        atomicAdd(&s_a1[l], xs.y * w);
        atomicMax(&s_m0[l], flipf(xs.x));
        atomicMax(&s_m1[l], flipf(xs.y));
    }
    if (threadIdx.x < BSZ) nodeBase[b * BSZ + threadIdx.x] = beg + off_s[threadIdx.x];
    if (threadIdx.x == BSZ) nodeBase[b * BSZ + BSZ] = end;  // benign same-value race
    __syncthreads();

    int t = threadIdx.x;
    if (t >= BSZ) return;
    int i = b * BSZ + t;
    if (i >= N_NODES) return;
    float2 xi = x[i];
    unsigned m0u = s_m0[t], m1u = s_m1[t];
    float m0 = m0u ? unflipf(m0u) : 0.0f;    // 0 sentinel == empty segment -> 0
    float m1 = m1u ? unflipf(m1u) : 0.0f;
    float4* pk = (float4*)(packed + ((size_t)i << 3));
    pk[0] = make_float4(xi.x, xi.y, s_a0[t], s_a1[t]);
    pk[1] = make_float4(m0, m1, 0.0f, 0.0f);
}

// -------- K5: fused layer-2 MAX+SUM aggregation in h1-feature space --------
// Linearity: Sum_e norm*(W2m_l@h1) == W2m_l@(Sum_e norm*h1)  -> accumulate
// sum per feature alongside max; W applied once per node in k6.
// Half-wave per node (lane f = feature), flat grid-stride for balance,
// unroll 8 => 16 edges in flight per wave. No atomics, plain stores.
__global__ __launch_bounds__(256, 4) void k5_agg(
        const float* __restrict__ packed, const int2* __restrict__ ebuf,
        const int* __restrict__ nodeBase,
        const float* __restrict__ w1m_l, const float* __restrict__ b1m,
        const float* __restrict__ w1m_r,
        const float* __restrict__ w1x_l, const float* __restrict__ b1x,
        const float* __restrict__ w1x_r,
        float* __restrict__ aggT) {
    int f = threadIdx.x & 31;
    float c0, c1, c2, c3, c4;
    int gsel;
    if (f < 24) {
        c0 = b1m[f];
        c1 = w1m_l[2 * f]; c2 = w1m_l[2 * f + 1];
        c3 = w1m_r[2 * f]; c4 = w1m_r[2 * f + 1];
        gsel = 2;                            // (a0,a1)
    } else {
        int g = f - 24;
        c0 = b1x[g];
        c1 = w1x_l[2 * g]; c2 = w1x_l[2 * g + 1];
        c3 = w1x_r[2 * g]; c4 = w1x_r[2 * g + 1];
        gsel = 4;                            // (m0,m1)
    }
    int h = (threadIdx.x >> 5) & 1;
    int wid = blockIdx.x * 4 + (threadIdx.x >> 6);

    for (int p = wid; p < NPAIR; p += K5_WAVES) {
        int i = 2 * p + h;
        int e0 = nodeBase[i], e1 = nodeBase[i + 1];
        float mx = 0.0f, sm = 0.0f;          // relu floor == empty-segment 0
        int e = e0;
        for (; e + 7 < e1; e += 8) {
            int2 rr[8];
#pragma unroll
            for (int j = 0; j < 8; j++) rr[j] = nt_load_rec(&ebuf[e + j]);
            float vv[8];
#pragma unroll
            for (int j = 0; j < 8; j++) {
                const float* row = packed + ((size_t)(rr[j].x >> 6) << 3);
                float2 xv = *(const float2*)row;
                float2 gv = *(const float2*)(row + gsel);
                vv[j] = fmaxf(c0 + c1 * gv.x + c2 * gv.y + c3 * xv.x + c4 * xv.y, 0.0f);
            }
#pragma unroll
            for (int j = 0; j < 8; j++) {
                mx = fmaxf(mx, vv[j]);
                sm = fmaf(__int_as_float(rr[j].y), vv[j], sm);
            }
        }
        for (; e < e1; e++) {
            int2 r = nt_load_rec(&ebuf[e]);
            const float* row = packed + ((size_t)(r.x >> 6) << 3);
            float2 xv = *(const float2*)row;
            float2 gv = *(const float2*)(row + gsel);
            float v = fmaxf(c0 + c1 * gv.x + c2 * gv.y + c3 * xv.x + c4 * xv.y, 0.0f);
            mx = fmaxf(mx, v);
            sm = fmaf(__int_as_float(r.y), v, sm);
        }
        float* o = aggT + ((size_t)i << 6);
        o[f] = mx;
        o[32 + f] = sm;
    }
}

// -------- K6: node-parallel final: W2m_l@sm + node2 + MLP head -> out --------
// sw: [0,48)w1m_l [48,72)b1m [72,120)w1m_r [120,136)w1x_l [136,144)b1x
//     [144,160)w1x_r [160,544)w2m_l [544,556)b2m [556,940)w2m_r [940,1068)w2x_l
//     [1068,1072)b2x [1072,1200)w2x_r [1200,1328)w3 [1328,1336)b3 [1336,1376)w4
//     [1376,1381)b4 [1381,1386)w5 [1386]b5
__global__ __launch_bounds__(256) void k6_final(
        const float* __restrict__ packed, const float* __restrict__ aggT,
        const float* __restrict__ w1m_l, const float* __restrict__ b1m,
        const float* __restrict__ w1m_r,
        const float* __restrict__ w1x_l, const float* __restrict__ b1x,
        const float* __restrict__ w1x_r,
        const float* __restrict__ w2m_l,
        const float* __restrict__ b2m, const float* __restrict__ w2m_r,
        const float* __restrict__ w2x_l, const float* __restrict__ b2x,
        const float* __restrict__ w2x_r,
        const float* __restrict__ w3, const float* __restrict__ b3,
        const float* __restrict__ w4, const float* __restrict__ b4,
        const float* __restrict__ w5, const float* __restrict__ b5,
        float* __restrict__ out) {
    __shared__ float sw[1387];
    for (int t = threadIdx.x; t < 1387; t += 256) {
        float v;
        if (t < 48)        v = w1m_l[t];
        else if (t < 72)   v = b1m[t - 48];
        else if (t < 120)  v = w1m_r[t - 72];
        else if (t < 136)  v = w1x_l[t - 120];
        else if (t < 144)  v = b1x[t - 136];
        else if (t < 160)  v = w1x_r[t - 144];
        else if (t < 544)  v = w2m_l[t - 160];
        else if (t < 556)  v = b2m[t - 544];
        else if (t < 940)  v = w2m_r[t - 556];
        else if (t < 1068) v = w2x_l[t - 940];
        else if (t < 1072) v = b2x[t - 1068];
        else if (t < 1200) v = w2x_r[t - 1072];
        else if (t < 1328) v = w3[t - 1200];
        else if (t < 1336) v = b3[t - 1328];
        else if (t < 1376) v = w4[t - 1336];
        else if (t < 1381) v = b4[t - 1376];
        else if (t < 1386) v = w5[t - 1381];
        else               v = b5[0];
        sw[t] = v;
    }
    __syncthreads();

    int i = blockIdx.x * blockDim.x + threadIdx.x;
    if (i >= N_NODES) return;

    const float4 pf = *(const float4*)(packed + ((size_t)i << 3));       // x0,x1,a0,a1
    const float2 pm = *(const float2*)(packed + ((size_t)i << 3) + 4);   // m0,m1
    float xi0 = pf.x, xi1 = pf.y, a0 = pf.z, a1 = pf.w, m0 = pm.x, m1 = pm.y;

    float mxv[32], smv[32];
    const float4* at = (const float4*)(aggT + ((size_t)i << 6));
#pragma unroll
    for (int q = 0; q < 8; q++) {
        float4 a = at[q];
        mxv[4 * q] = a.x; mxv[4 * q + 1] = a.y; mxv[4 * q + 2] = a.z; mxv[4 * q + 3] = a.w;
        float4 s = at[8 + q];
        smv[4 * q] = s.x; smv[4 * q + 1] = s.y; smv[4 * q + 2] = s.z; smv[4 * q + 3] = s.w;
    }

    float hh[32];
#pragma unroll
    for (int k = 0; k < 24; k++) {
        float v = sw[48 + k] + sw[2 * k] * a0 + sw[2 * k + 1] * a1
                + sw[72 + 2 * k] * xi0 + sw[72 + 2 * k + 1] * xi1;
        hh[k] = fmaxf(v, 0.0f);
    }
#pragma unroll
    for (int k = 0; k < 8; k++) {
        float v = sw[136 + k] + sw[120 + 2 * k] * m0 + sw[120 + 2 * k + 1] * m1
                + sw[144 + 2 * k] * xi0 + sw[144 + 2 * k + 1] * xi1;
        hh[24 + k] = fmaxf(v, 0.0f);
    }

    float h2[16];
#pragma unroll
    for (int j = 0; j < 12; j++) {
        float v = sw[544 + j];
#pragma unroll
        for (int k = 0; k < 32; k++)
            v += smv[k] * sw[160 + j * 32 + k] + hh[k] * sw[556 + j * 32 + k];
        h2[j] = fmaxf(v, 0.0f);
    }
#pragma unroll
    for (int j = 0; j < 4; j++) {
        float v = sw[1068 + j];
#pragma unroll
        for (int k = 0; k < 32; k++)
            v += mxv[k] * sw[940 + j * 32 + k] + hh[k] * sw[1072 + j * 32 + k];
        h2[12 + j] = fmaxf(v, 0.0f);
    }

    float t3[8];
#pragma unroll
    for (int j = 0; j < 8; j++) {
        float v = sw[1328 + j];
#pragma unroll
        for (int k = 0; k < 16; k++) v += h2[k] * sw[1200 + j * 16 + k];
        t3[j] = fmaxf(v, 0.0f);
    }
    float t4[5];
#pragma unroll
    for (int j = 0; j < 5; j++) {
        float v = sw[1376 + j];
#pragma unroll
        for (int k = 0; k < 8; k++) v += t3[k] * sw[1336 + j * 8 + k];
        t4[j] = fmaxf(v, 0.0f);
    }
    float o = sw[1386];
#pragma unroll
    for (int k = 0; k < 5; k++) o += t4[k] * sw[1381 + k];
    out[i] = o;
}

extern "C" void kernel_launch(void* const* d_in, const int* in_sizes, int n_in,
                              void* d_out, int out_size, void* d_ws, size_t ws_size,
                              hipStream_t stream) {
    const float* x     = (const float*)d_in[0];
    const int*   ei    = (const int*)d_in[1];
    const float* norm  = (const float*)d_in[2];
    const float* w1m_l = (const float*)d_in[3];
    const float* b1m   = (const float*)d_in[4];
    const float* w1m_r = (const float*)d_in[5];
    const float* w1x_l = (const float*)d_in[6];
    const float* b1x   = (const float*)d_in[7];
    const float* w1x_r = (const float*)d_in[8];
    const float* w2m_l = (const float*)d_in[9];
    const float* b2m   = (const float*)d_in[10];
    const float* w2m_r = (const float*)d_in[11];
    const float* w2x_l = (const float*)d_in[12];
    const float* b2x   = (const float*)d_in[13];
    const float* w2x_r = (const float*)d_in[14];
    const float* w3    = (const float*)d_in[15];
    const float* b3    = (const float*)d_in[16];
    const float* w4    = (const float*)d_in[17];
    const float* b4    = (const float*)d_in[18];
    const float* w5    = (const float*)d_in[19];
    const float* b5    = (const float*)d_in[20];
    float* out = (float*)d_out;

    // workspace (~54.5 MB)
    char* ws = (char*)d_ws;
    int2*  ebuf   = (int2*)ws;                               // 25.6 MB
    float* packed = (float*)(ws + (size_t)N_EDGES * 8);      // NPAD*8*4  = 3.2 MB
    float* aggT   = packed + (size_t)NPAD * 8;               // NPAD*64*4 = 25.6 MB
    int*   nodeBase   = (int*)(aggT + (size_t)NPAD * 64);    // NPAD+1
    int*   total      = nodeBase + NPAD + 1;                 // NBUCK
    int*   bucketBase = total + NBUCK;                       // NBUCK+1
    int*   cursor     = bucketBase + NBUCK + 1;              // NBUCK

    hipMemsetAsync(total, 0, NBUCK * sizeof(int), stream);

    k1_count    <<<K13_BLOCKS, 256, 0, stream>>>(ei + N_EDGES, total);
    k2_scan     <<<1, 512, 0, stream>>>(total, bucketBase, cursor);
    k3_scatter  <<<K13_BLOCKS, 256, 0, stream>>>(ei, norm, cursor, ebuf);
    k3b_sort_agg<<<NBUCK, 256, 0, stream>>>((const float2*)x, bucketBase, ebuf,
                                            nodeBase, packed);
    k5_agg      <<<K5_BLOCKS, 256, 0, stream>>>(packed, ebuf, nodeBase,
                                                w1m_l, b1m, w1m_r, w1x_l, b1x, w1x_r,
                                                aggT);
    k6_final    <<<(N_NODES + 255) / 256, 256, 0, stream>>>(packed, aggT,
                                                w1m_l, b1m, w1m_r, w1x_l, b1x, w1x_r,
                                                w2m_l, b2m, w2m_r, w2x_l, b2x, w2x_r,
                                                w3, b3, w4, b4, w5, b5, out);
}